// Round 8
// baseline (336.445 us; speedup 1.0000x reference)
//
#include <hip/hip_runtime.h>
#include <hip/hip_bf16.h>

typedef float f32x4 __attribute__((ext_vector_type(4)));
typedef short bf16x8 __attribute__((ext_vector_type(8)));
typedef short bf16x4 __attribute__((ext_vector_type(4)));

static __device__ __forceinline__ short f2bs(float f) {
  __hip_bfloat16 h = __float2bfloat16(f);
  union { __hip_bfloat16 h; short s; } u;
  u.h = h;
  return u.s;
}

// async global->LDS, 16B per lane; LDS dest = wave-uniform base + lane*16
#define GLDS(gp, lp) __builtin_amdgcn_global_load_lds( \
    (const __attribute__((address_space(1))) unsigned int*)(gp), \
    (__attribute__((address_space(3))) unsigned int*)(lp), 16, 0, 0)

#define MFMA16(a, b, c) __builtin_amdgcn_mfma_f32_16x16x32_bf16((a), (b), (c), 0, 0, 0)

// ---------------- fused preprocessing: one launch instead of three ----------
__global__ __launch_bounds__(256) void prep(const float* __restrict__ x,
                                            const float* __restrict__ w_qkv,
                                            const float* __restrict__ w_o,
                                            short* __restrict__ xb,
                                            short* __restrict__ wqkvT,
                                            short* __restrict__ woT) {
  __shared__ float tile[32][33];
  const int bid = blockIdx.x;
  if (bid < 8192) {
    int i = bid * 256 + threadIdx.x;
    f32x4 v = ((const f32x4*)x)[i];
    bf16x4 o;
    o[0] = f2bs(v[0]); o[1] = f2bs(v[1]); o[2] = f2bs(v[2]); o[3] = f2bs(v[3]);
    ((bf16x4*)xb)[i] = o;
    return;
  }
  const float* in; short* out; int R, C, bx, by;
  if (bid < 11264) {
    int b2 = bid - 8192;                 // 3072 blocks = 96 x 32
    in = w_qkv; out = wqkvT; R = 1024; C = 3072;
    bx = (b2 % 96) * 32; by = (b2 / 96) * 32;
  } else {
    int b3 = bid - 11264;                // 1024 blocks = 32 x 32
    in = w_o; out = woT; R = 1024; C = 1024;
    bx = (b3 % 32) * 32; by = (b3 / 32) * 32;
  }
  const int tx = threadIdx.x & 31;
  const int ty = threadIdx.x >> 5;
#pragma unroll
  for (int i = 0; i < 32; i += 8)
    tile[ty + i][tx] = in[(long)(by + ty + i) * C + bx + tx];
  __syncthreads();
#pragma unroll
  for (int i = 0; i < 32; i += 8)
    out[(long)(bx + ty + i) * R + by + tx] = f2bs(tile[tx][ty + i]);
}

// ======== 2-phase 128x128 mainloop (gemm_qkv + gemm_out) ========
// Round-7 post-mortem: 8-phase 256^2 port landed null (76.8 ~= 76.0 us,
// MfmaUtil ~26 both) — replicates the OPEN m232 quadrant; both schedules
// plateau at ~670 TF for a mechanism the counters don't isolate. Reverted
// to this simpler proven form (VGPR 48). Round-6 swizzle kept: LDS bank
// conflicts 6.29M -> 0 (verified).
__device__ __forceinline__ void gemm_compute_tile(const short* Ac, const short* Bc,
                                                  int r0, int c0, int lr, int quad,
                                                  f32x4 acc[4][4]) {
  const int rq = (quad ^ ((lr >> 1) & 3)) * 8;   // swizzled 16B-block offset
  bf16x8 af[4], bfr[4];
#pragma unroll
  for (int i = 0; i < 4; ++i)
    af[i] = *(const bf16x8*)(Ac + (r0 + i * 16 + lr) * 32 + rq);
#pragma unroll
  for (int j = 0; j < 4; ++j)
    bfr[j] = *(const bf16x8*)(Bc + (c0 + j * 16 + lr) * 32 + rq);
#pragma unroll
  for (int i = 0; i < 4; ++i)
#pragma unroll
    for (int j = 0; j < 4; ++j)
      acc[i][j] = MFMA16(af[i], bfr[j], acc[i][j]);
}

// NOTE round-2 lesson: do NOT force waves/EU via launch_bounds above 5 on
// kernels with a 64-reg accumulator — RA spills (1.7 GB scratch, 4.4x).
__device__ __forceinline__ void gemm_mainloop(const short* __restrict__ A,
                                              const short* __restrict__ Bt,
                                              int K, int rowA0, int rowB0,
                                              short* As, short* Bs,  // each 2*128*32
                                              f32x4 acc[4][4]) {
  const int tid = threadIdx.x;
  const int wave = tid >> 6;
  const int lane = tid & 63;
  const int lr = lane & 15;
  const int quad = lane >> 4;
  const int swz = ((lane & 3) ^ ((lane >> 3) & 3)) * 8;
  const short* aP = A + (long)(rowA0 + wave * 32 + (lane >> 2)) * K + swz;
  const short* bP = Bt + (long)(rowB0 + wave * 32 + (lane >> 2)) * K + swz;
  const int woff = wave * 32 * 32;
  const int r0 = (wave >> 1) * 64;
  const int c0 = (wave & 1) * 64;
  const int c16K = 16 * K;
  const int BUF = 128 * 32;
  GLDS(aP, As + woff);
  GLDS(aP + c16K, As + woff + 16 * 32);
  GLDS(bP, Bs + woff);
  GLDS(bP + c16K, Bs + woff + 16 * 32);
  aP += 32; bP += 32;
  const int nIter = K >> 5;   // even
#pragma unroll 1
  for (int i = 0; i < nIter; i += 2) {
    __syncthreads();
    if (i + 1 < nIter) {
      GLDS(aP, As + BUF + woff);
      GLDS(aP + c16K, As + BUF + woff + 16 * 32);
      GLDS(bP, Bs + BUF + woff);
      GLDS(bP + c16K, Bs + BUF + woff + 16 * 32);
      aP += 32; bP += 32;
    }
    gemm_compute_tile(As, Bs, r0, c0, lr, quad, acc);
    __syncthreads();
    if (i + 2 < nIter) {
      GLDS(aP, As + woff);
      GLDS(aP + c16K, As + woff + 16 * 32);
      GLDS(bP, Bs + woff);
      GLDS(bP + c16K, Bs + woff + 16 * 32);
      aP += 32; bP += 32;
    }
    gemm_compute_tile(As + BUF, Bs + BUF, r0, c0, lr, quad, acc);
  }
}

// ---------------- GEMM1: qkv = x @ w_qkv ----------------
__global__ __launch_bounds__(256, 5) void gemm_qkv(const short* __restrict__ xb,
                                                   const short* __restrict__ wT,
                                                   short* __restrict__ q,
                                                   short* __restrict__ k,
                                                   short* __restrict__ vt) {
  __shared__ __align__(16) short As[2 * 128 * 32];
  __shared__ __align__(16) short Bs[2 * 128 * 32];
  f32x4 acc[4][4];
#pragma unroll
  for (int i = 0; i < 4; ++i)
#pragma unroll
    for (int j = 0; j < 4; ++j)
      acc[i][j] = (f32x4){0.f, 0.f, 0.f, 0.f};
  const int tileM = blockIdx.x * 128;
  const int tileN = blockIdx.y * 128;
  gemm_mainloop(xb, wT, 1024, tileM, tileN, As, Bs, acc);
  const int tid = threadIdx.x;
  const int wave = tid >> 6;
  const int lane = tid & 63;
  const int lr = lane & 15;
  const int quad = lane >> 4;
  const int wrow = wave >> 1;      // 0..1
  const int wcol = wave & 1;       // 0..1
  // epilogue: scatter into q/k/v^T
#pragma unroll
  for (int i = 0; i < 4; ++i) {
    const int row0 = tileM + wrow * 64 + i * 16 + quad * 4;  // 4 consecutive rows
    const int b = row0 >> 11;
    const int t = row0 & 2047;
#pragma unroll
    for (int j = 0; j < 4; ++j) {
      int col = tileN + wcol * 64 + j * 16 + lr;
      int region = col >> 10;    // 0=q 1=k 2=v (wave-uniform)
      int w = col & 1023;
      int h = w >> 6;
      int d = w & 63;
      long bh = (long)b * 16 + h;
      if (region == 0) {
#pragma unroll
        for (int r = 0; r < 4; ++r)
          q[(bh * 2048 + t + r) * 64 + d] = f2bs(acc[i][j][r] * 0.03125f);  // fold 1/sqrt(C)
      } else if (region == 1) {
#pragma unroll
        for (int r = 0; r < 4; ++r)
          k[(bh * 2048 + t + r) * 64 + d] = f2bs(acc[i][j][r]);
      } else {
        bf16x4 pk;  // 4 consecutive t -> one b64 store into vt[bh][d][t..t+3]
#pragma unroll
        for (int r = 0; r < 4; ++r) pk[r] = f2bs(acc[i][j][r]);
        *(bf16x4*)(vt + (bh * 64 + d) * 2048 + t) = pk;
      }
    }
  }
}

// ---------------- flash attention with ALiBi + causal ----------------
// Round 8: K/V LDS staging REMOVED (guide common-mistake #7 / m169): K,V
// panels are L2/L3-resident (256 KB per (b,h); 32 MB total vs 256 MB L3),
// so kf/vf fragments are read directly from global. This deletes the K/V
// LDS writes AND both per-tile __syncthreads — Ps is wave-private, so the
// k-loop is barrier-free and waves progress independently. LDS 27.6->9.2 KB;
// launch_bounds (256,6) -> 24 waves/CU (VGPR cap 85 >> ~55 used; NOT 8/EU,
// which would spill per round-2 lesson). Cost: K-panel L2 traffic x4
// (~8 TB/s aggregate, well under 34.5 ceiling).
// h-mix remap (round 1) kept. ones-MFMA l-sum stays quarantined (round 4).
__global__ __launch_bounds__(256, 6) void attn(const short* __restrict__ q,
                                               const short* __restrict__ kk,
                                               const short* __restrict__ vt,
                                               short* __restrict__ cat) {
  __shared__ __align__(16) short Ps[4 * 16 * 72];   // per-wave P [m=16][k=64+pad]
  const int bx = blockIdx.x;                        // 0..2047
  const int g = bx >> 8;                            // residency round 0..7
  const int hshift = ((g & 1) << 3) | ((g & 2) << 1) | ((g & 4) >> 1);
  const int j = 31 - (bx >> 6);                     // q-tile index (64 rows)
  const int bh = (bx + hshift) & 63;                // h-mixed across CUs
  const int h = bh & 15;
  const int b = bh >> 4;
  const int tid = threadIdx.x;
  const int wave = tid >> 6;
  const int lane = tid & 63;
  const int lr = lane & 15;
  const int quad = lane >> 4;
  const float l2e = 1.44269504f;
  const float slope = exp2f(-0.5f * (float)(h + 1));   // 2^(-(h+1)/2)
  const float slope_l2e = slope * l2e;
  const float c2 = -2.0f * l2e;                        // fixed max = 2.0
  const int d_cut = (int)ceilf(20.0f * exp2f(0.5f * (float)(h + 1)));
  const short* kbg = kk + (long)bh * 2048 * 64;
  const short* vbg = vt + (long)bh * 64 * 2048;
  short* pw = Ps + wave * 16 * 72;

  const int q0 = j * 64;
  const int mrow0 = q0 + wave * 16;           // this wave's 16 q-rows (m = lr)
  const int kt_start = max(0, (q0 - d_cut) >> 6);
  const short* qptr = q + ((long)bh * 2048 + mrow0) * 64;
  bf16x8 qf0 = *(const bf16x8*)(qptr + (long)lr * 64 + quad * 8);
  bf16x8 qf1 = *(const bf16x8*)(qptr + (long)lr * 64 + 32 + quad * 8);
  float lp = 0.f;                             // per-lane partial row-sum (m=lr)
  f32x4 O[4];
#pragma unroll
  for (int dt = 0; dt < 4; ++dt) O[dt] = (f32x4){0.f, 0.f, 0.f, 0.f};
  // bias regs: bias[ct][r] = slope_l2e*(kbase + ct*16+quad*4+r - mrow0 - lr) + c2
  float bias[4][4];
  unsigned okbits = 0;                        // diag-tile causal mask (dist<=0)
#pragma unroll
  for (int ct = 0; ct < 4; ++ct)
#pragma unroll
    for (int r = 0; r < 4; ++r) {
      int off = ct * 16 + quad * 4 + r;
      bias[ct][r] = slope_l2e * (float)(kt_start * 64 + off - mrow0 - lr) + c2;
      if (off - wave * 16 - lr <= 0) okbits |= 1u << (ct * 4 + r);
    }
  const float bstep = slope_l2e * 64.0f;

  // per-lane fragment base pointers (advance by 64 shorts per k-tile)
  const short* kg = kbg + ((long)kt_start * 64 + lr) * 64 + quad * 8;   // K[t=kt*64+ct*16+lr][d=quad*8..]
  const short* vg = vbg + (long)lr * 2048 + kt_start * 64 + quad * 8;   // V^T[d=dt*16+lr][t=kt*64+quad*8..]

  for (int kt = kt_start; kt <= j; ++kt) {
    // S^T = K Q^T from global-resident K (L2/L3 hit)
    f32x4 S[4];
    __builtin_amdgcn_s_setprio(1);
#pragma unroll
    for (int ct = 0; ct < 4; ++ct) {
      bf16x8 kf0 = *(const bf16x8*)(kg + ct * 16 * 64);
      bf16x8 kf1 = *(const bf16x8*)(kg + ct * 16 * 64 + 32);
      f32x4 a = (f32x4){0.f, 0.f, 0.f, 0.f};
      a = MFMA16(kf0, qf0, a);
      a = MFMA16(kf1, qf1, a);
      S[ct] = a;
    }
    __builtin_amdgcn_s_setprio(0);
    // fixed-max softmax: p = exp2(S*l2e + bias)
    const bool diag = (kt == j);
#pragma unroll
    for (int ct = 0; ct < 4; ++ct) {
      bf16x4 pkt;
#pragma unroll
      for (int r = 0; r < 4; ++r) {
        float arg = fmaf(S[ct][r], l2e, bias[ct][r]);
        if (diag && !(okbits & (1u << (ct * 4 + r)))) arg = -10000.0f;  // causal
        float p = exp2f(arg);
        lp += p;
        pkt[r] = f2bs(p);
        bias[ct][r] += bstep;
      }
      // 4 consecutive k -> one b64 write into P[m=lr][k]
      *(bf16x4*)(pw + lr * 72 + ct * 16 + quad * 4) = pkt;
    }
    asm volatile("s_waitcnt lgkmcnt(0)" ::: "memory");  // wave-private scratch
    bf16x8 pf0 = *(const bf16x8*)(pw + lr * 72 + quad * 8);
    bf16x8 pf1 = *(const bf16x8*)(pw + lr * 72 + 32 + quad * 8);
    __builtin_amdgcn_s_setprio(1);
#pragma unroll
    for (int dt = 0; dt < 4; ++dt) {
      bf16x8 vf0 = *(const bf16x8*)(vg + dt * 16 * 2048);
      bf16x8 vf1 = *(const bf16x8*)(vg + dt * 16 * 2048 + 32);
      O[dt] = MFMA16(pf0, vf0, O[dt]);
      O[dt] = MFMA16(pf1, vf1, O[dt]);
    }
    __builtin_amdgcn_s_setprio(0);
    kg += 64 * 64;   // next k-tile rows
    vg += 64;        // next k-tile cols
  }
  // reduce l across the 4 quads (lane's partial covers k = {ct*16+quad*4+r})
  lp += __shfl_xor(lp, 16);
  lp += __shfl_xor(lp, 32);   // now every lane holds full l for row m = lr
  // epilogue: O rows are m = quad*4+r -> fetch l via shuffle
#pragma unroll
  for (int r = 0; r < 4; ++r) {
    float lm = __shfl(lp, quad * 4 + r);
    float inv = 1.0f / lm;
    int t = mrow0 + quad * 4 + r;
#pragma unroll
    for (int dt = 0; dt < 4; ++dt)
      cat[((long)b * 2048 + t) * 1024 + h * 64 + dt * 16 + lr] =
          f2bs(O[dt][r] * inv);
  }
}

// ---------------- GEMM2: out = concat @ w_o (fp32 out) ----------------
__global__ __launch_bounds__(256, 5) void gemm_out(const short* __restrict__ cat,
                                                   const short* __restrict__ woT,
                                                   float* __restrict__ out) {
  __shared__ __align__(16) short As[2 * 128 * 32];
  __shared__ __align__(16) short Bs[2 * 128 * 32];
  f32x4 acc[4][4];
#pragma unroll
  for (int i = 0; i < 4; ++i)
#pragma unroll
    for (int j = 0; j < 4; ++j)
      acc[i][j] = (f32x4){0.f, 0.f, 0.f, 0.f};
  const int tileM = blockIdx.x * 128;
  const int tileN = blockIdx.y * 128;
  gemm_mainloop(cat, woT, 1024, tileM, tileN, As, Bs, acc);
  const int tid = threadIdx.x;
  const int wave = tid >> 6;
  const int lane = tid & 63;
  const int lr = lane & 15;
  const int quad = lane >> 4;
#pragma unroll
  for (int i = 0; i < 4; ++i)
#pragma unroll
    for (int j = 0; j < 4; ++j) {
      int col = tileN + (wave & 1) * 64 + j * 16 + lr;
#pragma unroll
      for (int r = 0; r < 4; ++r) {
        int row = tileM + (wave >> 1) * 64 + i * 16 + quad * 4 + r;
        out[(long)row * 1024 + col] = acc[i][j][r];
      }
    }
}

extern "C" void kernel_launch(void* const* d_in, const int* in_sizes, int n_in,
                              void* d_out, int out_size, void* d_ws, size_t ws_size,
                              hipStream_t stream) {
  const float* x = (const float*)d_in[0];       // [4,2048,1024]
  const float* w_qkv = (const float*)d_in[1];   // [1024,3072]
  const float* w_o = (const float*)d_in[2];     // [1024,1024]
  float* out = (float*)d_out;                   // [4,2048,1024]
  short* ws = (short*)d_ws;
  short* xb = ws;                       // bf16 x; later reused as concat
  short* wqkvT = xb + 8388608;          // [3072][1024]
  short* woT = wqkvT + 3145728;         // [1024][1024]
  short* q = woT + 1048576;             // [B,H,T,dh], pre-scaled 1/32
  short* kb = q + 8388608;              // [B,H,T,dh]
  short* vt = kb + 8388608;             // [B,H,dh,T]

  prep<<<12288, 256, 0, stream>>>(x, w_qkv, w_o, xb, wqkvT, woT);
  gemm_qkv<<<dim3(64, 24), 256, 0, stream>>>(xb, wqkvT, q, kb, vt);
  attn<<<dim3(2048), 256, 0, stream>>>(q, kb, vt, xb /*concat reuses xb*/);
  gemm_out<<<dim3(64, 8), 256, 0, stream>>>(xb, woT, out);
}

// Round 9
// 321.429 us; speedup vs baseline: 1.0467x; 1.0467x over previous
//
#include <hip/hip_runtime.h>
#include <hip/hip_bf16.h>

typedef float f32x4 __attribute__((ext_vector_type(4)));
typedef short bf16x8 __attribute__((ext_vector_type(8)));
typedef short bf16x4 __attribute__((ext_vector_type(4)));

static __device__ __forceinline__ short f2bs(float f) {
  __hip_bfloat16 h = __float2bfloat16(f);
  union { __hip_bfloat16 h; short s; } u;
  u.h = h;
  return u.s;
}

// async global->LDS, 16B per lane; LDS dest = wave-uniform base + lane*16
#define GLDS(gp, lp) __builtin_amdgcn_global_load_lds( \
    (const __attribute__((address_space(1))) unsigned int*)(gp), \
    (__attribute__((address_space(3))) unsigned int*)(lp), 16, 0, 0)

#define MFMA16(a, b, c) __builtin_amdgcn_mfma_f32_16x16x32_bf16((a), (b), (c), 0, 0, 0)

// ---------------- fused preprocessing: one launch instead of three ----------
__global__ __launch_bounds__(256) void prep(const float* __restrict__ x,
                                            const float* __restrict__ w_qkv,
                                            const float* __restrict__ w_o,
                                            short* __restrict__ xb,
                                            short* __restrict__ wqkvT,
                                            short* __restrict__ woT) {
  __shared__ float tile[32][33];
  const int bid = blockIdx.x;
  if (bid < 8192) {
    int i = bid * 256 + threadIdx.x;
    f32x4 v = ((const f32x4*)x)[i];
    bf16x4 o;
    o[0] = f2bs(v[0]); o[1] = f2bs(v[1]); o[2] = f2bs(v[2]); o[3] = f2bs(v[3]);
    ((bf16x4*)xb)[i] = o;
    return;
  }
  const float* in; short* out; int R, C, bx, by;
  if (bid < 11264) {
    int b2 = bid - 8192;                 // 3072 blocks = 96 x 32
    in = w_qkv; out = wqkvT; R = 1024; C = 3072;
    bx = (b2 % 96) * 32; by = (b2 / 96) * 32;
  } else {
    int b3 = bid - 11264;                // 1024 blocks = 32 x 32
    in = w_o; out = woT; R = 1024; C = 1024;
    bx = (b3 % 32) * 32; by = (b3 / 32) * 32;
  }
  const int tx = threadIdx.x & 31;
  const int ty = threadIdx.x >> 5;
#pragma unroll
  for (int i = 0; i < 32; i += 8)
    tile[ty + i][tx] = in[(long)(by + ty + i) * C + bx + tx];
  __syncthreads();
#pragma unroll
  for (int i = 0; i < 32; i += 8)
    out[(long)(bx + ty + i) * R + by + tx] = f2bs(tile[tx][ty + i]);
}

// ======== 2-phase 128x128 mainloop (gemm_qkv + gemm_out) ========
// Round-7: 8-phase 256^2 port was null (~670 TF both) -> keep this simpler
// proven form. Round-6 swizzle kept (bank conflicts 6.29M -> 0, verified).
__device__ __forceinline__ void gemm_compute_tile(const short* Ac, const short* Bc,
                                                  int r0, int c0, int lr, int quad,
                                                  f32x4 acc[4][4]) {
  const int rq = (quad ^ ((lr >> 1) & 3)) * 8;   // swizzled 16B-block offset
  bf16x8 af[4], bfr[4];
#pragma unroll
  for (int i = 0; i < 4; ++i)
    af[i] = *(const bf16x8*)(Ac + (r0 + i * 16 + lr) * 32 + rq);
#pragma unroll
  for (int j = 0; j < 4; ++j)
    bfr[j] = *(const bf16x8*)(Bc + (c0 + j * 16 + lr) * 32 + rq);
#pragma unroll
  for (int i = 0; i < 4; ++i)
#pragma unroll
    for (int j = 0; j < 4; ++j)
      acc[i][j] = MFMA16(af[i], bfr[j], acc[i][j]);
}

// NOTE round-2 lesson: launch_bounds waves/EU > 5 on a 64-reg-acc kernel
// spills (1.7 GB scratch, 4.4x). Residency from geometry, not hints.
__device__ __forceinline__ void gemm_mainloop(const short* __restrict__ A,
                                              const short* __restrict__ Bt,
                                              int K, int rowA0, int rowB0,
                                              short* As, short* Bs,  // each 2*128*32
                                              f32x4 acc[4][4]) {
  const int tid = threadIdx.x;
  const int wave = tid >> 6;
  const int lane = tid & 63;
  const int lr = lane & 15;
  const int quad = lane >> 4;
  const int swz = ((lane & 3) ^ ((lane >> 3) & 3)) * 8;
  const short* aP = A + (long)(rowA0 + wave * 32 + (lane >> 2)) * K + swz;
  const short* bP = Bt + (long)(rowB0 + wave * 32 + (lane >> 2)) * K + swz;
  const int woff = wave * 32 * 32;
  const int r0 = (wave >> 1) * 64;
  const int c0 = (wave & 1) * 64;
  const int c16K = 16 * K;
  const int BUF = 128 * 32;
  GLDS(aP, As + woff);
  GLDS(aP + c16K, As + woff + 16 * 32);
  GLDS(bP, Bs + woff);
  GLDS(bP + c16K, Bs + woff + 16 * 32);
  aP += 32; bP += 32;
  const int nIter = K >> 5;   // even
#pragma unroll 1
  for (int i = 0; i < nIter; i += 2) {
    __syncthreads();
    if (i + 1 < nIter) {
      GLDS(aP, As + BUF + woff);
      GLDS(aP + c16K, As + BUF + woff + 16 * 32);
      GLDS(bP, Bs + BUF + woff);
      GLDS(bP + c16K, Bs + BUF + woff + 16 * 32);
      aP += 32; bP += 32;
    }
    gemm_compute_tile(As, Bs, r0, c0, lr, quad, acc);
    __syncthreads();
    if (i + 2 < nIter) {
      GLDS(aP, As + woff);
      GLDS(aP + c16K, As + woff + 16 * 32);
      GLDS(bP, Bs + woff);
      GLDS(bP + c16K, Bs + woff + 16 * 32);
      aP += 32; bP += 32;
    }
    gemm_compute_tile(As + BUF, Bs + BUF, r0, c0, lr, quad, acc);
  }
}

// ---------------- GEMM1: qkv = x @ w_qkv ----------------
__global__ __launch_bounds__(256, 5) void gemm_qkv(const short* __restrict__ xb,
                                                   const short* __restrict__ wT,
                                                   short* __restrict__ q,
                                                   short* __restrict__ k,
                                                   short* __restrict__ vt) {
  __shared__ __align__(16) short As[2 * 128 * 32];
  __shared__ __align__(16) short Bs[2 * 128 * 32];
  f32x4 acc[4][4];
#pragma unroll
  for (int i = 0; i < 4; ++i)
#pragma unroll
    for (int j = 0; j < 4; ++j)
      acc[i][j] = (f32x4){0.f, 0.f, 0.f, 0.f};
  const int tileM = blockIdx.x * 128;
  const int tileN = blockIdx.y * 128;
  gemm_mainloop(xb, wT, 1024, tileM, tileN, As, Bs, acc);
  const int tid = threadIdx.x;
  const int wave = tid >> 6;
  const int lane = tid & 63;
  const int lr = lane & 15;
  const int quad = lane >> 4;
  const int wrow = wave >> 1;      // 0..1
  const int wcol = wave & 1;       // 0..1
  // epilogue: scatter into q/k/v^T
#pragma unroll
  for (int i = 0; i < 4; ++i) {
    const int row0 = tileM + wrow * 64 + i * 16 + quad * 4;  // 4 consecutive rows
    const int b = row0 >> 11;
    const int t = row0 & 2047;
#pragma unroll
    for (int j = 0; j < 4; ++j) {
      int col = tileN + wcol * 64 + j * 16 + lr;
      int region = col >> 10;    // 0=q 1=k 2=v (wave-uniform)
      int w = col & 1023;
      int h = w >> 6;
      int d = w & 63;
      long bh = (long)b * 16 + h;
      if (region == 0) {
#pragma unroll
        for (int r = 0; r < 4; ++r)
          q[(bh * 2048 + t + r) * 64 + d] = f2bs(acc[i][j][r] * 0.03125f);  // fold 1/sqrt(C)
      } else if (region == 1) {
#pragma unroll
        for (int r = 0; r < 4; ++r)
          k[(bh * 2048 + t + r) * 64 + d] = f2bs(acc[i][j][r]);
      } else {
        bf16x4 pk;  // 4 consecutive t -> one b64 store into vt[bh][d][t..t+3]
#pragma unroll
        for (int r = 0; r < 4; ++r) pk[r] = f2bs(acc[i][j][r]);
        *(bf16x4*)(vt + (bh * 64 + d) * 2048 + t) = pk;
      }
    }
  }
}

// ---------------- flash attention with ALiBi + causal ----------------
// Round-8 lesson: MFMA fragment loads from GLOBAL are 16-way scatter-gathers
// (16B/lane at 128B-4KB stride) -> VMEM request-bound, 2.3x regression.
// Fragment reads must come from LDS; global reads stay linear. Reverted to
// staged K/V.
// Round 9: P LDS round-trip ELIMINATED via k-permutation. MFMA's K dim is a
// dummy index: permuting k consistently on A and B operands is exact.
// With sigma(q*8+j) = 4q+(j&3)+16*(j>>2), the PV A-operand fragment is
// concat(pkt[2kk], pkt[2kk+1]) — lane-local registers, no shuffles — and the
// V-operand becomes two bf16x4 reads at t=32kk+4quad(+16). Deletes 4
// ds_writes + lgkmcnt(0) drain + 2 ds_reads per tile, and frees Ps:
// LDS 27.6 -> 19.5 KB -> 8 blocks/CU (was 5). Pad 72->76: K-row b128 reads
// conflict-free (6*row mod 32 distinct for 16 rows). D-layout unchanged.
// h-mix remap (round 1) and setprio (round 5) kept; ones-MFMA l-sum stays
// quarantined (round 4).
__global__ __launch_bounds__(256, 6) void attn(const short* __restrict__ q,
                                               const short* __restrict__ kk,
                                               const short* __restrict__ vt,
                                               short* __restrict__ cat) {
  __shared__ __align__(16) short Ks[64 * 76];       // [kpos][dh], pad 76
  __shared__ __align__(16) short Vs[64 * 76];       // [d][kpos], pad 76
  const int bx = blockIdx.x;                        // 0..2047
  const int g = bx >> 8;                            // residency round 0..7
  const int hshift = ((g & 1) << 3) | ((g & 2) << 1) | ((g & 4) >> 1);
  const int j = 31 - (bx >> 6);                     // q-tile index (64 rows)
  const int bh = (bx + hshift) & 63;                // h-mixed across CUs
  const int h = bh & 15;
  const int b = bh >> 4;
  const int tid = threadIdx.x;
  const int wave = tid >> 6;
  const int lane = tid & 63;
  const int lr = lane & 15;
  const int quad = lane >> 4;
  const float l2e = 1.44269504f;
  const float slope = exp2f(-0.5f * (float)(h + 1));   // 2^(-(h+1)/2)
  const float slope_l2e = slope * l2e;
  const float c2 = -2.0f * l2e;                        // fixed max = 2.0
  const int d_cut = (int)ceilf(20.0f * exp2f(0.5f * (float)(h + 1)));
  const short* kbg = kk + (long)bh * 2048 * 64;
  const short* vbg = vt + (long)bh * 64 * 2048;
  const int srow = tid >> 3;          // 0..31
  const int scol = (tid & 7) * 8;     // 0..56

  const int q0 = j * 64;
  const int mrow0 = q0 + wave * 16;           // this wave's 16 q-rows (m = lr)
  const int kt_start = max(0, (q0 - d_cut) >> 6);
  const short* qptr = q + ((long)bh * 2048 + mrow0) * 64;
  bf16x8 qf0 = *(const bf16x8*)(qptr + (long)lr * 64 + quad * 8);
  bf16x8 qf1 = *(const bf16x8*)(qptr + (long)lr * 64 + 32 + quad * 8);
  float lp = 0.f;                             // per-lane partial row-sum (m=lr)
  f32x4 O[4];
#pragma unroll
  for (int dt = 0; dt < 4; ++dt) O[dt] = (f32x4){0.f, 0.f, 0.f, 0.f};
  // bias regs: bias[ct][r] = slope_l2e*(kbase + ct*16+quad*4+r - mrow0 - lr) + c2
  float bias[4][4];
  unsigned okbits = 0;                        // diag-tile causal mask (dist<=0)
#pragma unroll
  for (int ct = 0; ct < 4; ++ct)
#pragma unroll
    for (int r = 0; r < 4; ++r) {
      int off = ct * 16 + quad * 4 + r;
      bias[ct][r] = slope_l2e * (float)(kt_start * 64 + off - mrow0 - lr) + c2;
      if (off - wave * 16 - lr <= 0) okbits |= 1u << (ct * 4 + r);
    }
  const float bstep = slope_l2e * 64.0f;

  // prefetch first tile into registers
  const short* kg = kbg + (long)kt_start * 64 * 64;
  const short* vg = vbg + kt_start * 64;
  bf16x8 pk0 = *(const bf16x8*)(kg + srow * 64 + scol);
  bf16x8 pk1 = *(const bf16x8*)(kg + (srow + 32) * 64 + scol);
  bf16x8 pv0 = *(const bf16x8*)(vg + (long)srow * 2048 + scol);
  bf16x8 pv1 = *(const bf16x8*)(vg + (long)(srow + 32) * 2048 + scol);
  for (int kt = kt_start; kt <= j; ++kt) {
    *(bf16x8*)(Ks + srow * 76 + scol) = pk0;
    *(bf16x8*)(Ks + (srow + 32) * 76 + scol) = pk1;
    *(bf16x8*)(Vs + srow * 76 + scol) = pv0;
    *(bf16x8*)(Vs + (srow + 32) * 76 + scol) = pv1;
    __syncthreads();  // LDS tile ready
    if (kt < j) {     // issue next tile's loads; latency overlaps compute
      const short* kg2 = kbg + (long)(kt + 1) * 64 * 64;
      const short* vg2 = vbg + (kt + 1) * 64;
      pk0 = *(const bf16x8*)(kg2 + srow * 64 + scol);
      pk1 = *(const bf16x8*)(kg2 + (srow + 32) * 64 + scol);
      pv0 = *(const bf16x8*)(vg2 + (long)srow * 2048 + scol);
      pv1 = *(const bf16x8*)(vg2 + (long)(srow + 32) * 2048 + scol);
    }
    // S^T = K Q^T: lane holds S^T[k = kbase+ct*16+quad*4+r][m = mrow0+lr]
    f32x4 S[4];
    __builtin_amdgcn_s_setprio(1);
#pragma unroll
    for (int ct = 0; ct < 4; ++ct) {
      bf16x8 kf0 = *(const bf16x8*)(Ks + (ct * 16 + lr) * 76 + quad * 8);
      bf16x8 kf1 = *(const bf16x8*)(Ks + (ct * 16 + lr) * 76 + 32 + quad * 8);
      f32x4 a = (f32x4){0.f, 0.f, 0.f, 0.f};
      a = MFMA16(kf0, qf0, a);
      a = MFMA16(kf1, qf1, a);
      S[ct] = a;
    }
    __builtin_amdgcn_s_setprio(0);
    // fixed-max softmax: p = exp2(S*l2e + bias); P packed into registers
    // p8[kk][(ct&1)*4+r] = P[m=lr][t=16ct+4quad+r], kk = ct>>1
    const bool diag = (kt == j);
    bf16x8 p8[2];
#pragma unroll
    for (int ct = 0; ct < 4; ++ct) {
#pragma unroll
      for (int r = 0; r < 4; ++r) {
        float arg = fmaf(S[ct][r], l2e, bias[ct][r]);
        if (diag && !(okbits & (1u << (ct * 4 + r)))) arg = -10000.0f;  // causal
        float p = exp2f(arg);
        lp += p;
        p8[ct >> 1][(ct & 1) * 4 + r] = f2bs(p);
        bias[ct][r] += bstep;
      }
    }
    // PV with k-permuted operands (exact): A = p8[kk] (lane-local), B = V
    // fragments at t = 32kk + 4quad + r (+16).
    __builtin_amdgcn_s_setprio(1);
#pragma unroll
    for (int kk2 = 0; kk2 < 2; ++kk2) {
#pragma unroll
      for (int dt = 0; dt < 4; ++dt) {
        const short* vrow = Vs + (dt * 16 + lr) * 76 + kk2 * 32 + quad * 4;
        bf16x4 v0 = *(const bf16x4*)(vrow);
        bf16x4 v1 = *(const bf16x4*)(vrow + 16);
        bf16x8 vf;
#pragma unroll
        for (int e = 0; e < 4; ++e) { vf[e] = v0[e]; vf[4 + e] = v1[e]; }
        O[dt] = MFMA16(p8[kk2], vf, O[dt]);
      }
    }
    __builtin_amdgcn_s_setprio(0);
    __syncthreads();  // all waves done with Ks/Vs before next commit
  }
  // reduce l across the 4 quads (lane's partial covers k = {ct*16+quad*4+r})
  lp += __shfl_xor(lp, 16);
  lp += __shfl_xor(lp, 32);   // now every lane holds full l for row m = lr
  // epilogue: O rows are m = quad*4+r -> fetch l via shuffle
#pragma unroll
  for (int r = 0; r < 4; ++r) {
    float lm = __shfl(lp, quad * 4 + r);
    float inv = 1.0f / lm;
    int t = mrow0 + quad * 4 + r;
#pragma unroll
    for (int dt = 0; dt < 4; ++dt)
      cat[((long)b * 2048 + t) * 1024 + h * 64 + dt * 16 + lr] =
          f2bs(O[dt][r] * inv);
  }
}

// ---------------- GEMM2: out = concat @ w_o (fp32 out) ----------------
__global__ __launch_bounds__(256, 5) void gemm_out(const short* __restrict__ cat,
                                                   const short* __restrict__ woT,
                                                   float* __restrict__ out) {
  __shared__ __align__(16) short As[2 * 128 * 32];
  __shared__ __align__(16) short Bs[2 * 128 * 32];
  f32x4 acc[4][4];
#pragma unroll
  for (int i = 0; i < 4; ++i)
#pragma unroll
    for (int j = 0; j < 4; ++j)
      acc[i][j] = (f32x4){0.f, 0.f, 0.f, 0.f};
  const int tileM = blockIdx.x * 128;
  const int tileN = blockIdx.y * 128;
  gemm_mainloop(cat, woT, 1024, tileM, tileN, As, Bs, acc);
  const int tid = threadIdx.x;
  const int wave = tid >> 6;
  const int lane = tid & 63;
  const int lr = lane & 15;
  const int quad = lane >> 4;
#pragma unroll
  for (int i = 0; i < 4; ++i)
#pragma unroll
    for (int j = 0; j < 4; ++j) {
      int col = tileN + (wave & 1) * 64 + j * 16 + lr;
#pragma unroll
      for (int r = 0; r < 4; ++r) {
        int row = tileM + (wave >> 1) * 64 + i * 16 + quad * 4 + r;
        out[(long)row * 1024 + col] = acc[i][j][r];
      }
    }
}

extern "C" void kernel_launch(void* const* d_in, const int* in_sizes, int n_in,
                              void* d_out, int out_size, void* d_ws, size_t ws_size,
                              hipStream_t stream) {
  const float* x = (const float*)d_in[0];       // [4,2048,1024]
  const float* w_qkv = (const float*)d_in[1];   // [1024,3072]
  const float* w_o = (const float*)d_in[2];     // [1024,1024]
  float* out = (float*)d_out;                   // [4,2048,1024]
  short* ws = (short*)d_ws;
  short* xb = ws;                       // bf16 x; later reused as concat
  short* wqkvT = xb + 8388608;          // [3072][1024]
  short* woT = wqkvT + 3145728;         // [1024][1024]
  short* q = woT + 1048576;             // [B,H,T,dh], pre-scaled 1/32
  short* kb = q + 8388608;              // [B,H,T,dh]
  short* vt = kb + 8388608;             // [B,H,dh,T]

  prep<<<12288, 256, 0, stream>>>(x, w_qkv, w_o, xb, wqkvT, woT);
  gemm_qkv<<<dim3(64, 24), 256, 0, stream>>>(xb, wqkvT, q, kb, vt);
  attn<<<dim3(2048), 256, 0, stream>>>(q, kb, vt, xb /*concat reuses xb*/);
  gemm_out<<<dim3(64, 8), 256, 0, stream>>>(xb, woT, out);
}

// Round 10
// 233.998 us; speedup vs baseline: 1.4378x; 1.3736x over previous
//
#include <hip/hip_runtime.h>
#include <hip/hip_bf16.h>

typedef float f32x4 __attribute__((ext_vector_type(4)));
typedef short bf16x8 __attribute__((ext_vector_type(8)));
typedef short bf16x4 __attribute__((ext_vector_type(4)));

static __device__ __forceinline__ short f2bs(float f) {
  __hip_bfloat16 h = __float2bfloat16(f);
  union { __hip_bfloat16 h; short s; } u;
  u.h = h;
  return u.s;
}

// async global->LDS, 16B per lane; LDS dest = wave-uniform base + lane*16
#define GLDS(gp, lp) __builtin_amdgcn_global_load_lds( \
    (const __attribute__((address_space(1))) unsigned int*)(gp), \
    (__attribute__((address_space(3))) unsigned int*)(lp), 16, 0, 0)

#define MFMA16(a, b, c) __builtin_amdgcn_mfma_f32_16x16x32_bf16((a), (b), (c), 0, 0, 0)

// ---------------- fused preprocessing: one launch instead of three ----------
__global__ __launch_bounds__(256) void prep(const float* __restrict__ x,
                                            const float* __restrict__ w_qkv,
                                            const float* __restrict__ w_o,
                                            short* __restrict__ xb,
                                            short* __restrict__ wqkvT,
                                            short* __restrict__ woT) {
  __shared__ float tile[32][33];
  const int bid = blockIdx.x;
  if (bid < 8192) {
    int i = bid * 256 + threadIdx.x;
    f32x4 v = ((const f32x4*)x)[i];
    bf16x4 o;
    o[0] = f2bs(v[0]); o[1] = f2bs(v[1]); o[2] = f2bs(v[2]); o[3] = f2bs(v[3]);
    ((bf16x4*)xb)[i] = o;
    return;
  }
  const float* in; short* out; int R, C, bx, by;
  if (bid < 11264) {
    int b2 = bid - 8192;                 // 3072 blocks = 96 x 32
    in = w_qkv; out = wqkvT; R = 1024; C = 3072;
    bx = (b2 % 96) * 32; by = (b2 / 96) * 32;
  } else {
    int b3 = bid - 11264;                // 1024 blocks = 32 x 32
    in = w_o; out = woT; R = 1024; C = 1024;
    bx = (b3 % 32) * 32; by = (b3 / 32) * 32;
  }
  const int tx = threadIdx.x & 31;
  const int ty = threadIdx.x >> 5;
#pragma unroll
  for (int i = 0; i < 32; i += 8)
    tile[ty + i][tx] = in[(long)(by + ty + i) * C + bx + tx];
  __syncthreads();
#pragma unroll
  for (int i = 0; i < 32; i += 8)
    out[(long)(bx + ty + i) * R + by + tx] = f2bs(tile[tx][ty + i]);
}

// ======== 2-phase 128x128 mainloop (gemm_qkv + gemm_out) ========
// Round-7: 8-phase 256^2 port was null (~670 TF both) -> keep this simpler
// proven form. Round-6 swizzle kept (bank conflicts 6.29M -> 0, verified).
__device__ __forceinline__ void gemm_compute_tile(const short* Ac, const short* Bc,
                                                  int r0, int c0, int lr, int quad,
                                                  f32x4 acc[4][4]) {
  const int rq = (quad ^ ((lr >> 1) & 3)) * 8;   // swizzled 16B-block offset
  bf16x8 af[4], bfr[4];
#pragma unroll
  for (int i = 0; i < 4; ++i)
    af[i] = *(const bf16x8*)(Ac + (r0 + i * 16 + lr) * 32 + rq);
#pragma unroll
  for (int j = 0; j < 4; ++j)
    bfr[j] = *(const bf16x8*)(Bc + (c0 + j * 16 + lr) * 32 + rq);
#pragma unroll
  for (int i = 0; i < 4; ++i)
#pragma unroll
    for (int j = 0; j < 4; ++j)
      acc[i][j] = MFMA16(af[i], bfr[j], acc[i][j]);
}

// NOTE round-2 lesson (re-confirmed round 9 on attn): launch_bounds waves/EU
// above what the live-register count supports forces RA spill -> scratch
// FETCH/WRITE explosion. Residency from geometry, not hints.
__device__ __forceinline__ void gemm_mainloop(const short* __restrict__ A,
                                              const short* __restrict__ Bt,
                                              int K, int rowA0, int rowB0,
                                              short* As, short* Bs,  // each 2*128*32
                                              f32x4 acc[4][4]) {
  const int tid = threadIdx.x;
  const int wave = tid >> 6;
  const int lane = tid & 63;
  const int lr = lane & 15;
  const int quad = lane >> 4;
  const int swz = ((lane & 3) ^ ((lane >> 3) & 3)) * 8;
  const short* aP = A + (long)(rowA0 + wave * 32 + (lane >> 2)) * K + swz;
  const short* bP = Bt + (long)(rowB0 + wave * 32 + (lane >> 2)) * K + swz;
  const int woff = wave * 32 * 32;
  const int r0 = (wave >> 1) * 64;
  const int c0 = (wave & 1) * 64;
  const int c16K = 16 * K;
  const int BUF = 128 * 32;
  GLDS(aP, As + woff);
  GLDS(aP + c16K, As + woff + 16 * 32);
  GLDS(bP, Bs + woff);
  GLDS(bP + c16K, Bs + woff + 16 * 32);
  aP += 32; bP += 32;
  const int nIter = K >> 5;   // even
#pragma unroll 1
  for (int i = 0; i < nIter; i += 2) {
    __syncthreads();
    if (i + 1 < nIter) {
      GLDS(aP, As + BUF + woff);
      GLDS(aP + c16K, As + BUF + woff + 16 * 32);
      GLDS(bP, Bs + BUF + woff);
      GLDS(bP + c16K, Bs + BUF + woff + 16 * 32);
      aP += 32; bP += 32;
    }
    gemm_compute_tile(As, Bs, r0, c0, lr, quad, acc);
    __syncthreads();
    if (i + 2 < nIter) {
      GLDS(aP, As + woff);
      GLDS(aP + c16K, As + woff + 16 * 32);
      GLDS(bP, Bs + woff);
      GLDS(bP + c16K, Bs + woff + 16 * 32);
      aP += 32; bP += 32;
    }
    gemm_compute_tile(As + BUF, Bs + BUF, r0, c0, lr, quad, acc);
  }
}

// ---------------- GEMM1: qkv = x @ w_qkv ----------------
__global__ __launch_bounds__(256, 5) void gemm_qkv(const short* __restrict__ xb,
                                                   const short* __restrict__ wT,
                                                   short* __restrict__ q,
                                                   short* __restrict__ k,
                                                   short* __restrict__ vt) {
  __shared__ __align__(16) short As[2 * 128 * 32];
  __shared__ __align__(16) short Bs[2 * 128 * 32];
  f32x4 acc[4][4];
#pragma unroll
  for (int i = 0; i < 4; ++i)
#pragma unroll
    for (int j = 0; j < 4; ++j)
      acc[i][j] = (f32x4){0.f, 0.f, 0.f, 0.f};
  const int tileM = blockIdx.x * 128;
  const int tileN = blockIdx.y * 128;
  gemm_mainloop(xb, wT, 1024, tileM, tileN, As, Bs, acc);
  const int tid = threadIdx.x;
  const int wave = tid >> 6;
  const int lane = tid & 63;
  const int lr = lane & 15;
  const int quad = lane >> 4;
  const int wrow = wave >> 1;      // 0..1
  const int wcol = wave & 1;       // 0..1
  // epilogue: scatter into q/k/v^T
#pragma unroll
  for (int i = 0; i < 4; ++i) {
    const int row0 = tileM + wrow * 64 + i * 16 + quad * 4;  // 4 consecutive rows
    const int b = row0 >> 11;
    const int t = row0 & 2047;
#pragma unroll
    for (int j = 0; j < 4; ++j) {
      int col = tileN + wcol * 64 + j * 16 + lr;
      int region = col >> 10;    // 0=q 1=k 2=v (wave-uniform)
      int w = col & 1023;
      int h = w >> 6;
      int d = w & 63;
      long bh = (long)b * 16 + h;
      if (region == 0) {
#pragma unroll
        for (int r = 0; r < 4; ++r)
          q[(bh * 2048 + t + r) * 64 + d] = f2bs(acc[i][j][r] * 0.03125f);  // fold 1/sqrt(C)
      } else if (region == 1) {
#pragma unroll
        for (int r = 0; r < 4; ++r)
          k[(bh * 2048 + t + r) * 64 + d] = f2bs(acc[i][j][r]);
      } else {
        bf16x4 pk;  // 4 consecutive t -> one b64 store into vt[bh][d][t..t+3]
#pragma unroll
        for (int r = 0; r < 4; ++r) pk[r] = f2bs(acc[i][j][r]);
        *(bf16x4*)(vt + (bh * 64 + d) * 2048 + t) = pk;
      }
    }
  }
}

// ---------------- flash attention with ALiBi + causal ----------------
// Round-9 post-mortem: the k-permutation P-in-register form is CORRECT
// (passed, conflicts 0) but (256,6) capped VGPR at 40 -> full spill
// (WRITE 266MB scratch). Round 10: same kernel at (256,5) (cap ~102; est
// ~60-75 live regs -> no spill). Structure: staged K/V (round-8 lesson:
// global fragment reads are 16-way scatter-gathers, 2.3x loss), P stays in
// registers via k-index permutation sigma(q*8+j)=4q+(j&3)+16(j>>2) applied
// to BOTH PV operands (exact identity; deletes 4 ds_writes + lgkmcnt drain
// + 2 ds_reads per tile; Ps LDS freed: 27.6->19.5 KB). Pad 76: K-row b128
// reads conflict-free. h-mix remap (r1) + setprio (r5) kept; ones-MFMA
// l-sum quarantined (r4).
__global__ __launch_bounds__(256, 5) void attn(const short* __restrict__ q,
                                               const short* __restrict__ kk,
                                               const short* __restrict__ vt,
                                               short* __restrict__ cat) {
  __shared__ __align__(16) short Ks[64 * 76];       // [kpos][dh], pad 76
  __shared__ __align__(16) short Vs[64 * 76];       // [d][kpos], pad 76
  const int bx = blockIdx.x;                        // 0..2047
  const int g = bx >> 8;                            // residency round 0..7
  const int hshift = ((g & 1) << 3) | ((g & 2) << 1) | ((g & 4) >> 1);
  const int j = 31 - (bx >> 6);                     // q-tile index (64 rows)
  const int bh = (bx + hshift) & 63;                // h-mixed across CUs
  const int h = bh & 15;
  const int b = bh >> 4;
  const int tid = threadIdx.x;
  const int wave = tid >> 6;
  const int lane = tid & 63;
  const int lr = lane & 15;
  const int quad = lane >> 4;
  const float l2e = 1.44269504f;
  const float slope = exp2f(-0.5f * (float)(h + 1));   // 2^(-(h+1)/2)
  const float slope_l2e = slope * l2e;
  const float c2 = -2.0f * l2e;                        // fixed max = 2.0
  const int d_cut = (int)ceilf(20.0f * exp2f(0.5f * (float)(h + 1)));
  const short* kbg = kk + (long)bh * 2048 * 64;
  const short* vbg = vt + (long)bh * 64 * 2048;
  const int srow = tid >> 3;          // 0..31
  const int scol = (tid & 7) * 8;     // 0..56

  const int q0 = j * 64;
  const int mrow0 = q0 + wave * 16;           // this wave's 16 q-rows (m = lr)
  const int kt_start = max(0, (q0 - d_cut) >> 6);
  const short* qptr = q + ((long)bh * 2048 + mrow0) * 64;
  bf16x8 qf0 = *(const bf16x8*)(qptr + (long)lr * 64 + quad * 8);
  bf16x8 qf1 = *(const bf16x8*)(qptr + (long)lr * 64 + 32 + quad * 8);
  float lp = 0.f;                             // per-lane partial row-sum (m=lr)
  f32x4 O[4];
#pragma unroll
  for (int dt = 0; dt < 4; ++dt) O[dt] = (f32x4){0.f, 0.f, 0.f, 0.f};
  // bias regs: bias[ct][r] = slope_l2e*(kbase + ct*16+quad*4+r - mrow0 - lr) + c2
  float bias[4][4];
  unsigned okbits = 0;                        // diag-tile causal mask (dist<=0)
#pragma unroll
  for (int ct = 0; ct < 4; ++ct)
#pragma unroll
    for (int r = 0; r < 4; ++r) {
      int off = ct * 16 + quad * 4 + r;
      bias[ct][r] = slope_l2e * (float)(kt_start * 64 + off - mrow0 - lr) + c2;
      if (off - wave * 16 - lr <= 0) okbits |= 1u << (ct * 4 + r);
    }
  const float bstep = slope_l2e * 64.0f;

  // prefetch first tile into registers
  const short* kg = kbg + (long)kt_start * 64 * 64;
  const short* vg = vbg + kt_start * 64;
  bf16x8 pk0 = *(const bf16x8*)(kg + srow * 64 + scol);
  bf16x8 pk1 = *(const bf16x8*)(kg + (srow + 32) * 64 + scol);
  bf16x8 pv0 = *(const bf16x8*)(vg + (long)srow * 2048 + scol);
  bf16x8 pv1 = *(const bf16x8*)(vg + (long)(srow + 32) * 2048 + scol);
  for (int kt = kt_start; kt <= j; ++kt) {
    *(bf16x8*)(Ks + srow * 76 + scol) = pk0;
    *(bf16x8*)(Ks + (srow + 32) * 76 + scol) = pk1;
    *(bf16x8*)(Vs + srow * 76 + scol) = pv0;
    *(bf16x8*)(Vs + (srow + 32) * 76 + scol) = pv1;
    __syncthreads();  // LDS tile ready
    if (kt < j) {     // issue next tile's loads; latency overlaps compute
      const short* kg2 = kbg + (long)(kt + 1) * 64 * 64;
      const short* vg2 = vbg + (kt + 1) * 64;
      pk0 = *(const bf16x8*)(kg2 + srow * 64 + scol);
      pk1 = *(const bf16x8*)(kg2 + (srow + 32) * 64 + scol);
      pv0 = *(const bf16x8*)(vg2 + (long)srow * 2048 + scol);
      pv1 = *(const bf16x8*)(vg2 + (long)(srow + 32) * 2048 + scol);
    }
    // S^T = K Q^T: lane holds S^T[k = kbase+ct*16+quad*4+r][m = mrow0+lr]
    f32x4 S[4];
    __builtin_amdgcn_s_setprio(1);
#pragma unroll
    for (int ct = 0; ct < 4; ++ct) {
      bf16x8 kf0 = *(const bf16x8*)(Ks + (ct * 16 + lr) * 76 + quad * 8);
      bf16x8 kf1 = *(const bf16x8*)(Ks + (ct * 16 + lr) * 76 + 32 + quad * 8);
      f32x4 a = (f32x4){0.f, 0.f, 0.f, 0.f};
      a = MFMA16(kf0, qf0, a);
      a = MFMA16(kf1, qf1, a);
      S[ct] = a;
    }
    __builtin_amdgcn_s_setprio(0);
    // fixed-max softmax: p = exp2(S*l2e + bias); P packed into registers
    // p8[kk][(ct&1)*4+r] = P[m=lr][t=16ct+4quad+r], kk = ct>>1
    const bool diag = (kt == j);
    bf16x8 p8[2];
#pragma unroll
    for (int ct = 0; ct < 4; ++ct) {
#pragma unroll
      for (int r = 0; r < 4; ++r) {
        float arg = fmaf(S[ct][r], l2e, bias[ct][r]);
        if (diag && !(okbits & (1u << (ct * 4 + r)))) arg = -10000.0f;  // causal
        float p = exp2f(arg);
        lp += p;
        p8[ct >> 1][(ct & 1) * 4 + r] = f2bs(p);
        bias[ct][r] += bstep;
      }
    }
    // PV with k-permuted operands (exact): A = p8[kk] (lane-local), B = V
    // fragments at t = 32kk + 4quad + r (+16).
    __builtin_amdgcn_s_setprio(1);
#pragma unroll
    for (int kk2 = 0; kk2 < 2; ++kk2) {
#pragma unroll
      for (int dt = 0; dt < 4; ++dt) {
        const short* vrow = Vs + (dt * 16 + lr) * 76 + kk2 * 32 + quad * 4;
        bf16x4 v0 = *(const bf16x4*)(vrow);
        bf16x4 v1 = *(const bf16x4*)(vrow + 16);
        bf16x8 vf;
#pragma unroll
        for (int e = 0; e < 4; ++e) { vf[e] = v0[e]; vf[4 + e] = v1[e]; }
        O[dt] = MFMA16(p8[kk2], vf, O[dt]);
      }
    }
    __builtin_amdgcn_s_setprio(0);
    __syncthreads();  // all waves done with Ks/Vs before next commit
  }
  // reduce l across the 4 quads (lane's partial covers k = {ct*16+quad*4+r})
  lp += __shfl_xor(lp, 16);
  lp += __shfl_xor(lp, 32);   // now every lane holds full l for row m = lr
  // epilogue: O rows are m = quad*4+r -> fetch l via shuffle
#pragma unroll
  for (int r = 0; r < 4; ++r) {
    float lm = __shfl(lp, quad * 4 + r);
    float inv = 1.0f / lm;
    int t = mrow0 + quad * 4 + r;
#pragma unroll
    for (int dt = 0; dt < 4; ++dt)
      cat[((long)b * 2048 + t) * 1024 + h * 64 + dt * 16 + lr] =
          f2bs(O[dt][r] * inv);
  }
}

// ---------------- GEMM2: out = concat @ w_o (fp32 out) ----------------
__global__ __launch_bounds__(256, 5) void gemm_out(const short* __restrict__ cat,
                                                   const short* __restrict__ woT,
                                                   float* __restrict__ out) {
  __shared__ __align__(16) short As[2 * 128 * 32];
  __shared__ __align__(16) short Bs[2 * 128 * 32];
  f32x4 acc[4][4];
#pragma unroll
  for (int i = 0; i < 4; ++i)
#pragma unroll
    for (int j = 0; j < 4; ++j)
      acc[i][j] = (f32x4){0.f, 0.f, 0.f, 0.f};
  const int tileM = blockIdx.x * 128;
  const int tileN = blockIdx.y * 128;
  gemm_mainloop(cat, woT, 1024, tileM, tileN, As, Bs, acc);
  const int tid = threadIdx.x;
  const int wave = tid >> 6;
  const int lane = tid & 63;
  const int lr = lane & 15;
  const int quad = lane >> 4;
#pragma unroll
  for (int i = 0; i < 4; ++i)
#pragma unroll
    for (int j = 0; j < 4; ++j) {
      int col = tileN + (wave & 1) * 64 + j * 16 + lr;
#pragma unroll
      for (int r = 0; r < 4; ++r) {
        int row = tileM + (wave >> 1) * 64 + i * 16 + quad * 4 + r;
        out[(long)row * 1024 + col] = acc[i][j][r];
      }
    }
}

extern "C" void kernel_launch(void* const* d_in, const int* in_sizes, int n_in,
                              void* d_out, int out_size, void* d_ws, size_t ws_size,
                              hipStream_t stream) {
  const float* x = (const float*)d_in[0];       // [4,2048,1024]
  const float* w_qkv = (const float*)d_in[1];   // [1024,3072]
  const float* w_o = (const float*)d_in[2];     // [1024,1024]
  float* out = (float*)d_out;                   // [4,2048,1024]
  short* ws = (short*)d_ws;
  short* xb = ws;                       // bf16 x; later reused as concat
  short* wqkvT = xb + 8388608;          // [3072][1024]
  short* woT = wqkvT + 3145728;         // [1024][1024]
  short* q = woT + 1048576;             // [B,H,T,dh], pre-scaled 1/32
  short* kb = q + 8388608;              // [B,H,T,dh]
  short* vt = kb + 8388608;             // [B,H,dh,T]

  prep<<<12288, 256, 0, stream>>>(x, w_qkv, w_o, xb, wqkvT, woT);
  gemm_qkv<<<dim3(64, 24), 256, 0, stream>>>(xb, wqkvT, q, kb, vt);
  attn<<<dim3(2048), 256, 0, stream>>>(q, kb, vt, xb /*concat reuses xb*/);
  gemm_out<<<dim3(64, 8), 256, 0, stream>>>(xb, woT, out);
}